// Round 1
// baseline (307.150 us; speedup 1.0000x reference)
//
#include <hip/hip_runtime.h>

// Soft-argmax over channel groups:
//   x_in: (4, 14, 1024, 1024) fp32 NCHW
//   out:  (4, 2, 1024, 1024)  fp32 NCHW
//   out[b,o,h,w] = sum_k softmax_k(x[b, o*7+k, h, w]) * (k - 3)
//
// HBM-bound: 235 MB in + 33.5 MB out => ~43 us floor at 6.3 TB/s.
// One thread = one output group = 4 contiguous pixels of ONE output channel
// (7 plane loads + 1 store). Nontemporal hints: pure streaming, zero reuse.
//
// R0 change: hard-code the (fixed) problem geometry instead of deriving the
// thread count from in_sizes[0] (ambiguous bytes-vs-elements semantics; if it
// was bytes, the old grid was 4x too large => 4x HBM traffic + silent OOB).
// n = 4*2*(1024*1024/4) = 2^21 threads, grid = 8192 * 256 exactly, no tail.
// Also: num/den via v_rcp_f32 (tolerance is bf16-loose; saves the ~10-op
// precise-div sequence per pixel).

#define HW4_LOG2 18         // (H*W)/4 in float4 units
#define K 7
#define NTHREADS (1 << 21)  // B * OUT_CH * HW/4 = 4*2*262144

typedef float f32x4 __attribute__((ext_vector_type(4)));

__global__ __launch_bounds__(256) void softargmax_kernel(
    const f32x4* __restrict__ x, f32x4* __restrict__ out)
{
    const int tid = blockIdx.x * blockDim.x + threadIdx.x;
    const int g   = tid >> HW4_LOG2;                 // b*2 + o  (0..7)
    const int sp4 = tid & ((1 << HW4_LOG2) - 1);     // spatial float4 index

    // input plane index of this group's first channel: b*14 + o*7 = 7*g
    const f32x4* __restrict__ src = x + (((long long)(7 * g)) << HW4_LOG2) + sp4;

    // Load all 7 channel values for the 4 pixels. v[k] = channel k (4 pixels).
    f32x4 v[K];
    #pragma unroll
    for (int k = 0; k < K; ++k)
        v[k] = __builtin_nontemporal_load(&src[(long long)k << HW4_LOG2]);

    f32x4 res;
    #pragma unroll
    for (int j = 0; j < 4; ++j) {
        // stabilized softmax weighted sum over K=7, weights (k-3)
        float m = v[0][j];
        #pragma unroll
        for (int k = 1; k < K; ++k) m = fmaxf(m, v[k][j]);
        float num = 0.0f, den = 0.0f;
        #pragma unroll
        for (int k = 0; k < K; ++k) {
            float e = __expf(v[k][j] - m);
            num = fmaf(e, (float)(k - 3), num);
            den += e;
        }
        res[j] = num * __builtin_amdgcn_rcpf(den);  // den in [1,7]; ~1ulp rcp
    }
    // output plane index = b*2 + o = g
    __builtin_nontemporal_store(res, &out[(((long long)g) << HW4_LOG2) + sp4]);
}

extern "C" void kernel_launch(void* const* d_in, const int* in_sizes, int n_in,
                              void* d_out, int out_size, void* d_ws, size_t ws_size,
                              hipStream_t stream) {
    (void)in_sizes; (void)n_in; (void)d_ws; (void)ws_size; (void)out_size;
    const f32x4* x = (const f32x4*)d_in[0];
    f32x4* out = (f32x4*)d_out;
    const int block = 256;
    const int grid = NTHREADS / block;   // 8192, exact — no tail check needed
    softargmax_kernel<<<grid, block, 0, stream>>>(x, out);
}